// Round 6
// baseline (1190.240 us; speedup 1.0000x reference)
//
#include <hip/hip_runtime.h>
#include <cstdint>
#include <cstddef>

#define NN 262144
#define EE 1048576
#define BB 512
#define SEG 512

// ---------------- Threefry-2x32 (exact JAX replica) ----------------
__device__ __forceinline__ unsigned rotl32(unsigned x, int r) {
    return (x << r) | (x >> (32 - r));
}

__device__ __forceinline__ void tf2x32(unsigned k0, unsigned k1, unsigned x0, unsigned x1,
                                       unsigned& o0, unsigned& o1) {
    unsigned ks[3] = {k0, k1, k0 ^ k1 ^ 0x1BD11BDAu};
    x0 += ks[0]; x1 += ks[1];
    const int R0[4] = {13, 15, 26, 6};
    const int R1[4] = {17, 29, 16, 24};
#pragma unroll
    for (int i = 0; i < 5; ++i) {
        const int* R = (i & 1) ? R1 : R0;
#pragma unroll
        for (int j = 0; j < 4; ++j) {
            x0 += x1;
            x1 = rotl32(x1, R[j]);
            x1 ^= x0;
        }
        x0 += ks[(i + 1) % 3];
        x1 += ks[(i + 2) % 3] + (unsigned)(i + 1);
    }
    o0 = x0; o1 = x1;
}

__device__ __forceinline__ float unif_loc(unsigned idx) {
    unsigned j = idx & (NN / 2 - 1);
    unsigned half = idx >> 17;
    unsigned o0, o1;
    tf2x32(0u, 42u, j, j + (unsigned)(NN / 2), o0, o1);
    unsigned bits = half ? o1 : o0;
    float f = __uint_as_float((bits >> 9) | 0x3F800000u) - 1.0f;
    const float minv = 1e-6f;
    const float maxv = 1.0f - 1e-6f;
    const float span = maxv - minv;
    return fmaxf(minv, __fadd_rn(__fmul_rn(f, span), minv));
}

// ---------------- async global->LDS (16B/lane, wave-uniform LDS base) ----------------
__device__ __forceinline__ void gload_lds16(const float* g, float* l) {
    __builtin_amdgcn_global_load_lds((const __attribute__((address_space(1))) unsigned int*)g,
                                     (__attribute__((address_space(3))) unsigned int*)l, 16, 0, 0);
}

// ---------------- CSR build ----------------
__global__ void csr_count(const int* __restrict__ dst, int* __restrict__ counts, int E) {
    int i = blockIdx.x * 256 + threadIdx.x;
    if (i < E) atomicAdd(&counts[dst[i]], 1);
}

__global__ void scan512(const int* __restrict__ in, int* __restrict__ outExcl, int* __restrict__ bsum) {
    __shared__ int s[512];
    int b = blockIdx.x, tid = threadIdx.x;
    int v = in[(size_t)b * 512 + tid];
    s[tid] = v;
    __syncthreads();
    for (int d = 1; d < 512; d <<= 1) {
        int add = (tid >= d) ? s[tid - d] : 0;
        __syncthreads();
        s[tid] += add;
        __syncthreads();
    }
    outExcl[(size_t)b * 512 + tid] = s[tid] - v;
    if (tid == 511) bsum[b] = s[511];
}

__global__ void scan_fix(int* __restrict__ offs, const int* __restrict__ bbase,
                         int* __restrict__ cursor, int N, int E) {
    int gid = blockIdx.x * 512 + threadIdx.x;
    int v = offs[gid] + bbase[blockIdx.x];
    offs[gid] = v;
    cursor[gid] = v;
    if (gid == 0) offs[N] = E;
}

__global__ void csr_fill(const int* __restrict__ dst, const int* __restrict__ src,
                         const float4* __restrict__ ea, int* __restrict__ cursor,
                         int* __restrict__ ssrc, float4* __restrict__ sea, int E) {
    int i = blockIdx.x * 256 + threadIdx.x;
    if (i < E) {
        int p = atomicAdd(&cursor[dst[i]], 1);
        ssrc[p] = src[i];
        sea[p] = ea[i];
    }
}

// ---------------- Layer 0: aggregate (dim 8) ----------------
__global__ void agg_l0(const float* __restrict__ x, const int* __restrict__ ssrc,
                       const float4* __restrict__ sea, const int* __restrict__ offs,
                       const float* __restrict__ We0, const float* __restrict__ be0,
                       float* __restrict__ out) {
    __shared__ float Ws[32];
    __shared__ float bs[8];
    int tid = threadIdx.x;
    if (tid < 32) Ws[tid] = We0[tid];
    if (tid < 8) bs[tid] = be0[tid];
    __syncthreads();
    int n = blockIdx.x * 256 + tid;
    float a[8] = {0.f, 0.f, 0.f, 0.f, 0.f, 0.f, 0.f, 0.f};
    int pb = offs[n], pe = offs[n + 1];
    for (int p = pb; p < pe; ++p) {
        int s = ssrc[p];
        float4 ev = sea[p];
        float4 xa = *(const float4*)(x + (size_t)s * 8);
        float4 xb = *(const float4*)(x + (size_t)s * 8 + 4);
        float xs[8] = {xa.x, xa.y, xa.z, xa.w, xb.x, xb.y, xb.z, xb.w};
#pragma unroll
        for (int j2 = 0; j2 < 8; ++j2) {
            float m = xs[j2] + bs[j2] + ev.x * Ws[j2] + ev.y * Ws[8 + j2] +
                      ev.z * Ws[16 + j2] + ev.w * Ws[24 + j2];
            a[j2] += fmaxf(m, 0.f);
        }
    }
    float4 o0 = {a[0], a[1], a[2], a[3]};
    float4 o1 = {a[4], a[5], a[6], a[7]};
    *(float4*)(out + (size_t)n * 8) = o0;
    *(float4*)(out + (size_t)n * 8 + 4) = o1;
}

// ---------------- Layer 0 update ----------------
__global__ void update_l0(const float* __restrict__ x, const float* __restrict__ agg0,
                          const float* __restrict__ W0, const float* __restrict__ b0,
                          float* __restrict__ h1) {
    __shared__ float Ws[8 * 128];
    __shared__ float bs[128];
    __shared__ float ts[2][8];
    int tid = threadIdx.x;
#pragma unroll
    for (int i = tid; i < 1024; i += 256) Ws[i] = W0[i];
    if (tid < 128) bs[tid] = b0[tid];
    int sub = tid >> 7;
    int c = tid & 127;
    int node = blockIdx.x * 2 + sub;
    if (c < 8) ts[sub][c] = x[(size_t)node * 8 + c] + agg0[(size_t)node * 8 + c];
    __syncthreads();
    float acc = bs[c];
#pragma unroll
    for (int k = 0; k < 8; ++k) acc = fmaf(ts[sub][k], Ws[k * 128 + c], acc);
    h1[(size_t)node * 128 + c] = fmaxf(acc, 0.f);
}

// ---------------- Layers 1,2: fused msg+aggregate, 2 nodes per wave ----------------
// Lane owns 4 dims (float4); half-wave per node; one b128 h-gather covers 2 edges.
__global__ __launch_bounds__(256) void agg_l(const float* __restrict__ h,
                                             const int* __restrict__ ssrc,
                                             const float4* __restrict__ sea,
                                             const int* __restrict__ offs,
                                             const float* __restrict__ We,
                                             const float* __restrict__ be,
                                             float* __restrict__ out) {
    int tid = threadIdx.x;
    int lane = tid & 63;
    int half = lane >> 5;
    int dl = lane & 31;   // dims 4dl..4dl+3
    int node = blockIdx.x * 8 + (tid >> 6) * 2 + half;
    float4 w0 = *(const float4*)(We + 4 * dl);
    float4 w1 = *(const float4*)(We + 128 + 4 * dl);
    float4 w2 = *(const float4*)(We + 256 + 4 * dl);
    float4 w3 = *(const float4*)(We + 384 + 4 * dl);
    float4 bv = *(const float4*)(be + 4 * dl);
    int pb = offs[node], pe = offs[node + 1];
    int deg = pe - pb;
    int dmax = max(deg, __shfl_xor(deg, 32, 64));
    float4 acc = {0.f, 0.f, 0.f, 0.f};
    for (int t = 0; t < dmax; ++t) {
        int p = pb + t;
        bool act = p < pe;
        int pc = min(p, max(pe - 1, 0));
        int s = ssrc[pc];
        float4 ev = sea[pc];
        float4 hv = *(const float4*)(h + (size_t)s * 128 + 4 * dl);
        float4 m;
        m.x = hv.x + bv.x + ev.x * w0.x + ev.y * w1.x + ev.z * w2.x + ev.w * w3.x;
        m.y = hv.y + bv.y + ev.x * w0.y + ev.y * w1.y + ev.z * w2.y + ev.w * w3.y;
        m.z = hv.z + bv.z + ev.x * w0.z + ev.y * w1.z + ev.z * w2.z + ev.w * w3.z;
        m.w = hv.w + bv.w + ev.x * w0.w + ev.y * w1.w + ev.z * w2.w + ev.w * w3.w;
        acc.x += act ? fmaxf(m.x, 0.f) : 0.f;
        acc.y += act ? fmaxf(m.y, 0.f) : 0.f;
        acc.z += act ? fmaxf(m.z, 0.f) : 0.f;
        acc.w += act ? fmaxf(m.w, 0.f) : 0.f;
    }
    *(float4*)(out + (size_t)node * 128 + 4 * dl) = acc;
}

// ====== 128x128-tile GEMM pass: reg-prefetched A/Q, W via global_load_lds ======
// Per kc: [sync] issue W async load + write prefetched A regs to LDS (transposed,
// stride 132); [sync] prefetch next A/Q (lands during FMA phase); compute.
// Thread owns rows 8ty..8ty+7, cols {4tx..4tx+3, 64+4tx..64+4tx+3}.
// In-place safe: block reads only rows r0..r0+127 and all reads precede writes.
__device__ __forceinline__ void mm_pass(const float* __restrict__ P, const float* Q,
                                        const float* __restrict__ W,
                                        float (&As)[32][132], float (&Ws)[32][128],
                                        float (&acc)[8][8], int r0) {
    const int tid = threadIdx.x;
    const int ty = tid >> 4, tx = tid & 15;
    const int lane = tid & 63, wv = tid >> 6;
    float4 pa[4], qa[4];
#pragma unroll
    for (int i = 0; i < 4; ++i) {
        int f = tid + 256 * i;
        int r = f >> 3, c4 = f & 7;
        size_t g = (size_t)(r0 + r) * 128 + 4 * c4;
        pa[i] = *(const float4*)(P + g);
        if (Q) qa[i] = *(const float4*)(Q + g);
    }
    for (int kc = 0; kc < 4; ++kc) {
        const int k0 = kc * 32;
        __syncthreads();   // LDS free (prev compute done); drains prefetch loads
#pragma unroll
        for (int i = 0; i < 4; ++i) {
            int kRow = 8 * wv + 2 * i;
            gload_lds16(W + (size_t)(k0 + kRow) * 128 + 4 * lane, &Ws[kRow][0]);
        }
#pragma unroll
        for (int i = 0; i < 4; ++i) {
            int f = tid + 256 * i;
            int r = f >> 3, c4 = f & 7;
            float4 pv = pa[i];
            if (Q) {
                float4 qv = qa[i];
                pv.x += qv.x; pv.y += qv.y; pv.z += qv.z; pv.w += qv.w;
            }
            As[4 * c4 + 0][r] = pv.x;
            As[4 * c4 + 1][r] = pv.y;
            As[4 * c4 + 2][r] = pv.z;
            As[4 * c4 + 3][r] = pv.w;
        }
        __syncthreads();   // Ws loaded (vmcnt) + As visible (lgkm)
        if (kc < 3) {      // prefetch next chunk; completes during FMA phase
#pragma unroll
            for (int i = 0; i < 4; ++i) {
                int f = tid + 256 * i;
                int r = f >> 3, c4 = f & 7;
                size_t g = (size_t)(r0 + r) * 128 + (k0 + 32) + 4 * c4;
                pa[i] = *(const float4*)(P + g);
                if (Q) qa[i] = *(const float4*)(Q + g);
            }
        }
#pragma unroll 4
        for (int k = 0; k < 32; ++k) {
            float4 a0 = *(const float4*)&As[k][8 * ty];
            float4 a1 = *(const float4*)&As[k][8 * ty + 4];
            float4 w0 = *(const float4*)&Ws[k][4 * tx];
            float4 w1 = *(const float4*)&Ws[k][64 + 4 * tx];
            float av[8] = {a0.x, a0.y, a0.z, a0.w, a1.x, a1.y, a1.z, a1.w};
            float wn[8] = {w0.x, w0.y, w0.z, w0.w, w1.x, w1.y, w1.z, w1.w};
#pragma unroll
            for (int m = 0; m < 8; ++m)
#pragma unroll
                for (int n = 0; n < 8; ++n)
                    acc[m][n] = fmaf(av[m], wn[n], acc[m][n]);
        }
    }
}

__global__ __launch_bounds__(256, 4) void gemm_k(const float* __restrict__ P, const float* Q,
                                                 const float* __restrict__ W,
                                                 const float* __restrict__ bias,
                                                 float* __restrict__ out) {
    __shared__ float As[32][132];
    __shared__ float Ws[32][128];
    int r0 = blockIdx.x * 128;
    int ty = threadIdx.x >> 4, tx = threadIdx.x & 15;
    float acc[8][8] = {};
    mm_pass(P, Q, W, As, Ws, acc, r0);
    float4 b0 = *(const float4*)(bias + 4 * tx);
    float4 b1 = *(const float4*)(bias + 64 + 4 * tx);
#pragma unroll
    for (int m = 0; m < 8; ++m) {
        float4 o0, o1;
        o0.x = fmaxf(acc[m][0] + b0.x, 0.f);
        o0.y = fmaxf(acc[m][1] + b0.y, 0.f);
        o0.z = fmaxf(acc[m][2] + b0.z, 0.f);
        o0.w = fmaxf(acc[m][3] + b0.w, 0.f);
        o1.x = fmaxf(acc[m][4] + b1.x, 0.f);
        o1.y = fmaxf(acc[m][5] + b1.y, 0.f);
        o1.z = fmaxf(acc[m][6] + b1.z, 0.f);
        o1.w = fmaxf(acc[m][7] + b1.w, 0.f);
        size_t g = (size_t)(r0 + 8 * ty + m) * 128;
        *(float4*)(out + g + 4 * tx) = o0;
        *(float4*)(out + g + 64 + 4 * tx) = o1;
    }
}

// ---- layer-3 GEMM + fused location-actor head (emb -> hidden -> logit) ----
__global__ __launch_bounds__(256, 4) void gemm_emb_logit(
        const float* __restrict__ P, const float* Q,
        const float* __restrict__ W, const float* __restrict__ bias,
        float* __restrict__ emb,
        const float* __restrict__ aW1, const float* __restrict__ ab1,
        const float* __restrict__ aW2, const float* __restrict__ ab2,
        float* __restrict__ L) {
    __shared__ float As[32][132];
    __shared__ float Ws[32][128];
    int r0 = blockIdx.x * 128;
    int ty = threadIdx.x >> 4, tx = threadIdx.x & 15;
    {
        float acc[8][8] = {};
        mm_pass(P, Q, W, As, Ws, acc, r0);
        float4 b0 = *(const float4*)(bias + 4 * tx);
        float4 b1 = *(const float4*)(bias + 64 + 4 * tx);
#pragma unroll
        for (int m = 0; m < 8; ++m) {
            float4 o0, o1;
            o0.x = fmaxf(acc[m][0] + b0.x, 0.f);
            o0.y = fmaxf(acc[m][1] + b0.y, 0.f);
            o0.z = fmaxf(acc[m][2] + b0.z, 0.f);
            o0.w = fmaxf(acc[m][3] + b0.w, 0.f);
            o1.x = fmaxf(acc[m][4] + b1.x, 0.f);
            o1.y = fmaxf(acc[m][5] + b1.y, 0.f);
            o1.z = fmaxf(acc[m][6] + b1.z, 0.f);
            o1.w = fmaxf(acc[m][7] + b1.w, 0.f);
            size_t g = (size_t)(r0 + 8 * ty + m) * 128;
            *(float4*)(emb + g + 4 * tx) = o0;
            *(float4*)(emb + g + 64 + 4 * tx) = o1;
        }
    }
    __syncthreads();   // drain stores; emb rows r0.. visible to whole block
    {
        float acc[8][8] = {};
        mm_pass(emb, nullptr, aW1, As, Ws, acc, r0);
        float4 b0 = *(const float4*)(ab1 + 4 * tx);
        float4 b1 = *(const float4*)(ab1 + 64 + 4 * tx);
        float4 wa = *(const float4*)(aW2 + 4 * tx);
        float4 wb = *(const float4*)(aW2 + 64 + 4 * tx);
        float b2v = ab2[0];
#pragma unroll
        for (int m = 0; m < 8; ++m) {
            float v = fmaxf(acc[m][0] + b0.x, 0.f) * wa.x;
            v += fmaxf(acc[m][1] + b0.y, 0.f) * wa.y;
            v += fmaxf(acc[m][2] + b0.z, 0.f) * wa.z;
            v += fmaxf(acc[m][3] + b0.w, 0.f) * wa.w;
            v += fmaxf(acc[m][4] + b1.x, 0.f) * wb.x;
            v += fmaxf(acc[m][5] + b1.y, 0.f) * wb.y;
            v += fmaxf(acc[m][6] + b1.z, 0.f) * wb.z;
            v += fmaxf(acc[m][7] + b1.w, 0.f) * wb.w;
            v += __shfl_down(v, 8, 16);
            v += __shfl_down(v, 4, 16);
            v += __shfl_down(v, 2, 16);
            v += __shfl_down(v, 1, 16);
            if (tx == 0) L[r0 + 8 * ty + m] = v + b2v;
        }
    }
}

// ---------------- per-graph softmax + Gumbel-max sampling ----------------
__global__ void sample_k(const float* __restrict__ L, float* __restrict__ ob,
                         int* __restrict__ locInt) {
    int g = blockIdx.x, tid = threadIdx.x;
    __shared__ float sh[512];
    __shared__ float rb[256];
    __shared__ int ib[256];
    float l0 = L[g * 512 + tid];
    float l1 = L[g * 512 + 256 + tid];
    rb[tid] = fmaxf(l0, l1);
    __syncthreads();
    for (int s2 = 128; s2 > 0; s2 >>= 1) {
        if (tid < s2) rb[tid] = fmaxf(rb[tid], rb[tid + s2]);
        __syncthreads();
    }
    float mx = rb[0];
    __syncthreads();
    float s0 = l0 - mx, s1 = l1 - mx;
    sh[tid] = s0; sh[256 + tid] = s1;
    float e0 = expf(s0), e1 = expf(s1);
    rb[tid] = e0 + e1;
    __syncthreads();
    for (int s2 = 128; s2 > 0; s2 >>= 1) {
        if (tid < s2) rb[tid] += rb[tid + s2];
        __syncthreads();
    }
    float denom = rb[0];
    __syncthreads();
    rb[tid] = e0 * s0 + e1 * s1;
    __syncthreads();
    for (int s2 = 128; s2 > 0; s2 >>= 1) {
        if (tid < s2) rb[tid] += rb[tid + s2];
        __syncthreads();
    }
    float sum2 = rb[0];
    __syncthreads();
    unsigned i0 = (unsigned)(g * 512 + tid);
    unsigned i1 = i0 + 256u;
    float p0 = l0 - logf(-logf(unif_loc(i0)));
    float p1 = l1 - logf(-logf(unif_loc(i1)));
    rb[tid] = fmaxf(p0, p1);
    __syncthreads();
    for (int s2 = 128; s2 > 0; s2 >>= 1) {
        if (tid < s2) rb[tid] = fmaxf(rb[tid], rb[tid + s2]);
        __syncthreads();
    }
    float pmax = rb[0];
    __syncthreads();
    int c0 = (p0 >= pmax) ? tid : 0x7FFFFFFF;
    int c1 = (p1 >= pmax) ? (tid + 256) : 0x7FFFFFFF;
    ib[tid] = min(c0, c1);
    __syncthreads();
    for (int s2 = 128; s2 > 0; s2 >>= 1) {
        if (tid < s2) ib[tid] = min(ib[tid], ib[tid + s2]);
        __syncthreads();
    }
    if (tid == 0) {
        int li = ib[0];
        float logD = logf(denom);
        ob[g] = (float)(g * 512 + li);
        ob[1024 + g] = sh[li] - logD;
        ob[2048 + g] = logD - sum2 / denom;
        locInt[g] = g * 512 + li;
    }
}

// ---------------- pooled = segment_sum(emb) ----------------
__global__ void pool_k(const float* __restrict__ emb, float* __restrict__ pooled) {
    int g = blockIdx.x, tid = threadIdx.x;
    int c = tid & 127, rg = tid >> 7;
    __shared__ float sh[512];
    float s0 = 0.f, s1 = 0.f, s2 = 0.f, s3 = 0.f;
    const float* base = emb + ((size_t)g * 512 + (size_t)rg * 128) * 128 + c;
    for (int n = 0; n < 128; n += 4) {
        s0 += base[(size_t)(n + 0) * 128];
        s1 += base[(size_t)(n + 1) * 128];
        s2 += base[(size_t)(n + 2) * 128];
        s3 += base[(size_t)(n + 3) * 128];
    }
    sh[tid] = (s0 + s1) + (s2 + s3);
    __syncthreads();
    if (rg == 0) pooled[g * 128 + c] = sh[c] + sh[128 + c] + sh[256 + c] + sh[384 + c];
}

// ---------------- heads ----------------
__global__ void heads_k(const float* __restrict__ emb, const float* __restrict__ pooled,
                        const int* __restrict__ locInt,
                        const float* __restrict__ maW1, const float* __restrict__ mab1,
                        const float* __restrict__ maW2, const float* __restrict__ mab2,
                        const float* __restrict__ lcW1, const float* __restrict__ lcb1,
                        const float* __restrict__ lcW2, const float* __restrict__ lcb2,
                        const float* __restrict__ mcW1, const float* __restrict__ mcb1,
                        const float* __restrict__ mcW2, const float* __restrict__ mcb2,
                        float* __restrict__ ob) {
    int g = blockIdx.x, tid = threadIdx.x;
    __shared__ float sel[128], pl[128];
    __shared__ float red[4][128];
    __shared__ float red1[128];
    __shared__ float mcv_sh;
    sel[tid] = emb[(size_t)locInt[g] * 128 + tid];
    pl[tid] = pooled[g * 128 + tid];
    __syncthreads();
    float h = mab1[tid];
    for (int k = 0; k < 128; ++k) h = fmaf(sel[k], maW1[k * 128 + tid], h);
    h = fmaxf(h, 0.f);
    red[0][tid] = h * maW2[tid * 4 + 0];
    red[1][tid] = h * maW2[tid * 4 + 1];
    red[2][tid] = h * maW2[tid * 4 + 2];
    red[3][tid] = h * maW2[tid * 4 + 3];
    __syncthreads();
    for (int s2 = 64; s2 > 0; s2 >>= 1) {
        if (tid < s2) {
            red[0][tid] += red[0][tid + s2];
            red[1][tid] += red[1][tid + s2];
            red[2][tid] += red[2][tid + s2];
            red[3][tid] += red[3][tid + s2];
        }
        __syncthreads();
    }
    float h2 = mcb1[tid];
    for (int k = 0; k < 128; ++k) h2 = fmaf(sel[k], mcW1[k * 128 + tid], h2);
    h2 = fmaxf(h2, 0.f);
    red1[tid] = h2 * mcW2[tid];
    __syncthreads();
    for (int s2 = 64; s2 > 0; s2 >>= 1) {
        if (tid < s2) red1[tid] += red1[tid + s2];
        __syncthreads();
    }
    if (tid == 0) mcv_sh = red1[0] + mcb2[0];
    __syncthreads();
    float h3 = lcb1[tid];
    for (int k = 0; k < 128; ++k) h3 = fmaf(pl[k], lcW1[k * 128 + tid], h3);
    h3 = fmaxf(h3, 0.f);
    red1[tid] = h3 * lcW2[tid];
    __syncthreads();
    for (int s2 = 64; s2 > 0; s2 >>= 1) {
        if (tid < s2) red1[tid] += red1[tid + s2];
        __syncthreads();
    }
    if (tid == 0) {
        float lcv = red1[0] + lcb2[0];
        float lg[4];
#pragma unroll
        for (int c = 0; c < 4; ++c) lg[c] = red[c][0] + mab2[c];
        unsigned fk0, fk1;
        tf2x32(0u, 42u, 0u, 1u, fk0, fk1);
        float gmb[4];
#pragma unroll
        for (int c = 0; c < 4; ++c) {
            unsigned m = (unsigned)(g * 4 + c);
            unsigned j = m & 1023u;
            unsigned halfb = m >> 10;
            unsigned o0, o1;
            tf2x32(fk0, fk1, j, j + 1024u, o0, o1);
            unsigned bits = halfb ? o1 : o0;
            float f = __uint_as_float((bits >> 9) | 0x3F800000u) - 1.0f;
            const float tiny = 1.17549435e-38f;
            float u = fmaxf(tiny, __fadd_rn(__fmul_rn(f, 1.0f), tiny));
            gmb[c] = -logf(-logf(u));
        }
        int best = 0;
        float bz = gmb[0] + lg[0];
#pragma unroll
        for (int c = 1; c < 4; ++c) {
            float z = gmb[c] + lg[c];
            if (z > bz) { bz = z; best = c; }
        }
        float M = fmaxf(fmaxf(lg[0], lg[1]), fmaxf(lg[2], lg[3]));
        float se = 0.f;
#pragma unroll
        for (int c = 0; c < 4; ++c) se += expf(lg[c] - M);
        float lse = M + logf(se);
        float ent = 0.f;
#pragma unroll
        for (int c = 0; c < 4; ++c) {
            float lp = lg[c] - lse;
            ent -= expf(lp) * lp;
        }
        ob[512 + g] = (float)best;
        ob[1536 + g] = lg[best] - lse;
        ob[2560 + g] = ent;
        ob[3072 + g] = lcv;
        ob[3584 + g] = mcv_sh;
    }
}

// ---------------- launch ----------------
extern "C" void kernel_launch(void* const* d_in, const int* in_sizes, int n_in,
                              void* d_out, int out_size, void* d_ws, size_t ws_size,
                              hipStream_t stream) {
    const float* x   = (const float*)d_in[0];
    const int* ei    = (const int*)d_in[1];
    const float* ea  = (const float*)d_in[2];
    const float* We0 = (const float*)d_in[5];
    const float* be0 = (const float*)d_in[6];
    const float* W0  = (const float*)d_in[7];
    const float* b0  = (const float*)d_in[8];
    const float* We1 = (const float*)d_in[9];
    const float* be1 = (const float*)d_in[10];
    const float* W1  = (const float*)d_in[11];
    const float* b1  = (const float*)d_in[12];
    const float* We2 = (const float*)d_in[13];
    const float* be2 = (const float*)d_in[14];
    const float* W2  = (const float*)d_in[15];
    const float* b2  = (const float*)d_in[16];
    const float* laW1 = (const float*)d_in[17];
    const float* lab1 = (const float*)d_in[18];
    const float* laW2 = (const float*)d_in[19];
    const float* lab2 = (const float*)d_in[20];
    const float* maW1 = (const float*)d_in[21];
    const float* mab1 = (const float*)d_in[22];
    const float* maW2 = (const float*)d_in[23];
    const float* mab2 = (const float*)d_in[24];
    const float* lcW1 = (const float*)d_in[25];
    const float* lcb1 = (const float*)d_in[26];
    const float* lcW2 = (const float*)d_in[27];
    const float* lcb2 = (const float*)d_in[28];
    const float* mcW1 = (const float*)d_in[29];
    const float* mcb1 = (const float*)d_in[30];
    const float* mcW2 = (const float*)d_in[31];
    const float* mcb2 = (const float*)d_in[32];

    float* out = (float*)d_out;
    char* ws = (char*)d_ws;
    size_t off = 0;
    auto alloc = [&](size_t bytes) -> void* {
        void* p = ws + off;
        off += (bytes + 255) & ~(size_t)255;
        return p;
    };
    float* U    = (float*)alloc((size_t)NN * 128 * 4);  // 128 MB ping-pong
    int* counts = (int*)alloc((size_t)NN * 4);
    int* offs   = (int*)alloc((size_t)(NN + 1) * 4);
    int* cursor = (int*)alloc((size_t)NN * 4);
    int* ssrc   = (int*)alloc((size_t)EE * 4);
    float4* sea = (float4*)alloc((size_t)EE * 16);
    int* bsum   = (int*)alloc(512 * 4);
    int* bbase  = (int*)alloc(512 * 4);
    int* bscr   = (int*)alloc(512 * 4);
    float* Lg   = (float*)alloc((size_t)NN * 4);
    float* pooled = (float*)alloc((size_t)BB * 128 * 4);
    int* locInt = (int*)alloc((size_t)BB * 4);

    const int* src = ei;
    const int* dstA = ei + EE;
    float* V = out + 4096;
    float* agg0 = U;

    hipMemsetAsync(counts, 0, (size_t)NN * 4, stream);
    csr_count<<<EE / 256, 256, 0, stream>>>(dstA, counts, EE);
    scan512<<<NN / 512, 512, 0, stream>>>(counts, offs, bsum);
    scan512<<<1, 512, 0, stream>>>(bsum, bbase, bscr);
    scan_fix<<<NN / 512, 512, 0, stream>>>(offs, bbase, cursor, NN, EE);
    csr_fill<<<EE / 256, 256, 0, stream>>>(dstA, src, (const float4*)ea, cursor, ssrc, sea, EE);

    agg_l0<<<NN / 256, 256, 0, stream>>>(x, ssrc, sea, offs, We0, be0, agg0);
    update_l0<<<NN / 2, 256, 0, stream>>>(x, agg0, W0, b0, V);
    agg_l<<<NN / 8, 256, 0, stream>>>(V, ssrc, sea, offs, We1, be1, U);
    gemm_k<<<NN / 128, 256, 0, stream>>>(V, U, W1, b1, U);
    agg_l<<<NN / 8, 256, 0, stream>>>(U, ssrc, sea, offs, We2, be2, V);
    gemm_emb_logit<<<NN / 128, 256, 0, stream>>>(U, V, W2, b2, V,
                                                 laW1, lab1, laW2, lab2, Lg);
    sample_k<<<BB, 256, 0, stream>>>(Lg, out, locInt);
    pool_k<<<BB, 512, 0, stream>>>(V, pooled);
    heads_k<<<BB, 128, 0, stream>>>(V, pooled, locInt, maW1, mab1, maW2, mab2,
                                    lcW1, lcb1, lcW2, lcb2, mcW1, mcb1, mcW2, mcb2, out);
}